// Round 9
// baseline (1061.243 us; speedup 1.0000x reference)
//
#include <hip/hip_runtime.h>
#include <hip/hip_bf16.h>
#include <stdint.h>

#define S 2048
#define D 64
#define H 4096
#define NB 8

typedef __bf16 bf16;
typedef __attribute__((ext_vector_type(8))) __bf16 bf16x8;
typedef __attribute__((ext_vector_type(4))) __bf16 bf16x4;
typedef __attribute__((ext_vector_type(4))) float f32x4;

// Raw LDS-DMA, invisible to the compiler's waitcnt pass. (R5-verified.)
__device__ __forceinline__ void dma16_raw(const bf16* g, uint32_t m0_bytes) {
  uint32_t m0s = __builtin_amdgcn_readfirstlane(m0_bytes);
  asm volatile("s_mov_b32 m0, %1\n\t"
               "global_load_lds_dwordx4 %0, off"
               :: "v"(g), "s"(m0s) : "memory");
}

__device__ __forceinline__ uint32_t lds_off_bytes(const void* p) {
  return (uint32_t)(uintptr_t)(__attribute__((address_space(3))) const void*)p;
}

// ---------------------------------------------------------------------------
__global__ __launch_bounds__(256) void transpose_cast(const float* __restrict__ W,
                                                      bf16* __restrict__ Wt,
                                                      int K, int N) {
  __shared__ float tile[64][65];
  int k0 = blockIdx.y * 64, n0 = blockIdx.x * 64;
  int c = threadIdx.x & 63;
  int r4 = threadIdx.x >> 6;
#pragma unroll
  for (int i = 0; i < 16; ++i) {
    int r = i * 4 + r4;
    tile[r][c] = W[(size_t)(k0 + r) * N + n0 + c];
  }
  __syncthreads();
#pragma unroll
  for (int i = 0; i < 16; ++i) {
    int r = i * 4 + r4;
    Wt[(size_t)(n0 + r) * K + k0 + c] = (bf16)tile[c][r];
  }
}

// ---------------------------------------------------------------------------
__global__ __launch_bounds__(256) void cast_bf16(const float* __restrict__ x,
                                                 bf16* __restrict__ y) {
  int i = blockIdx.x * 256 + threadIdx.x;
  f32x4 v = ((const f32x4*)x)[i];
  bf16x4 o;
  o[0] = (bf16)v.x; o[1] = (bf16)v.y; o[2] = (bf16)v.z; o[3] = (bf16)v.w;
  ((bf16x4*)y)[i] = o;
}

// ---------------------------------------------------------------------------
// GEMM: C[M][N] = epilogue(scale * (A[M][K] @ Bt[N][K]^T) + bias[N])
// 128x256 block tile, BK=32, 4 waves (64x128 each). R8 post-mortem: the
// [read-burst][MFMA-burst] phases ran serially (1378 = 760 LDS + 620 MFMA
// cyc/block-iter). Fix: register-double-buffered fragments, ONE barrier per
// K-step, 4 LDS buffers (96 KB), 1 wave/SIMD (launch_bounds(256,1) -> 512
// regs; 2 frag sets + 128-reg acc ~ 270, no spill).
// Iter it: DMA t(it+2)->buf (it+2)&3; vmcnt(6)+barrier (tile it+1 landed
// everywhere); ds_read frags(it+1) from buf (it+1)&3; 32 MFMA on frags(it)
// already in regs (needs only lgkmcnt(12) -> issues immediately, overlapping
// the reads). Buffer-overwrite safety: buf (it+2)&3 holds tile it-2, whose
// frag reads were forced complete by MFMA(it-2)'s implicit lgkm wait, two
// barriers ago. XOR swizzle (0 bank conflicts) retained.
// ---------------------------------------------------------------------------
template <int RELU, int OUTBF16>
__global__ __launch_bounds__(256, 1) void gemm_bt(const bf16* __restrict__ A,
                                                  const bf16* __restrict__ Bt,
                                                  const float* __restrict__ bias,
                                                  void* __restrict__ Cv,
                                                  float scale,
                                                  int M, int N, int K,
                                                  long strideA, long strideB,
                                                  long strideC) {
  // smem (bf16 elems): A bufs b*4096, b=0..3 [0,16384); B bufs 16384+b*8192.
  __shared__ __align__(16) bf16 smem[49152];  // 96 KB
  int tid = threadIdx.x;
  int lane = tid & 63;
  int w = tid >> 6;

  int m0 = blockIdx.y * 128, n0 = blockIdx.x * 256;
  const bf16* Ab = A + (size_t)blockIdx.z * strideA;
  const bf16* Btb = Bt + (size_t)blockIdx.z * strideB;

  int grow = tid >> 2;
  int gcol = (((lane & 3) ^ ((lane >> 3) & 3)) * 8);
  const bf16* gA0 = Ab + (size_t)(m0 + grow) * K + gcol;
  const bf16* gA1 = gA0 + (size_t)64 * K;
  const bf16* gB0 = Btb + (size_t)(n0 + grow) * K + gcol;
  const bf16* gB1 = gB0 + (size_t)64 * K;
  const bf16* gB2 = gB0 + (size_t)128 * K;
  const bf16* gB3 = gB0 + (size_t)192 * K;

  uint32_t ldsBase = lds_off_bytes(&smem[0]);
  uint32_t wb = (uint32_t)(w * 1024);
  uint32_t mA[4], mB[4];
#pragma unroll
  for (int b = 0; b < 4; ++b) {
    mA[b] = ldsBase + b * 8192 + wb;
    mB[b] = ldsBase + 32768 + b * 16384 + wb;
  }

  int mw = (w & 1) * 64, nw = (w >> 1) * 128;
  int lr = lane & 15;
  int ck = lane >> 4;
  int swz = (ck ^ ((lr >> 1) & 3)) * 8;
  const bf16* paBase = smem + (size_t)(mw + lr) * 32 + swz;          // + buf*4096
  const bf16* pbBase = smem + 16384 + (size_t)(nw + lr) * 32 + swz;  // + buf*8192

  f32x4 zero = {0.f, 0.f, 0.f, 0.f};
  f32x4 acc[4][8];
#pragma unroll
  for (int mt = 0; mt < 4; ++mt)
#pragma unroll
    for (int nt = 0; nt < 8; ++nt) acc[mt][nt] = zero;

  const int niter = K / 32;

  bf16x8 F0a[4], F0b[8], F1a[4], F1b[8];

#define STAGE(buf, koff)                                 \
  do {                                                   \
    dma16_raw(gA0 + (koff), mA[buf]);                    \
    dma16_raw(gA1 + (koff), mA[buf] + 4096);             \
    dma16_raw(gB0 + (koff), mB[buf]);                    \
    dma16_raw(gB1 + (koff), mB[buf] + 4096);             \
    dma16_raw(gB2 + (koff), mB[buf] + 8192);             \
    dma16_raw(gB3 + (koff), mB[buf] + 12288);            \
  } while (0)

#define READF(Fa, Fb, buf)                                                    \
  do {                                                                        \
    const bf16* pa_ = paBase + (buf) * 4096;                                  \
    const bf16* pb_ = pbBase + (buf) * 8192;                                  \
    _Pragma("unroll")                                                         \
    for (int mt = 0; mt < 4; ++mt) Fa[mt] = *(const bf16x8*)(pa_ + mt * 512); \
    _Pragma("unroll")                                                         \
    for (int nt = 0; nt < 8; ++nt) Fb[nt] = *(const bf16x8*)(pb_ + nt * 512); \
  } while (0)

#define MFMAF(Fa, Fb)                                                         \
  do {                                                                        \
    _Pragma("unroll")                                                         \
    for (int mt = 0; mt < 4; ++mt)                                            \
      _Pragma("unroll")                                                       \
      for (int nt = 0; nt < 8; ++nt)                                          \
        acc[mt][nt] = __builtin_amdgcn_mfma_f32_16x16x32_bf16(Fa[mt], Fb[nt], \
                                                              acc[mt][nt], 0, 0, 0); \
  } while (0)

#define KPRE(it) ((it) + 2 < niter ? ((it) + 2) * 32 : (niter - 1) * 32)

#define ITER(it, bufP, bufR, FaC, FbC, FaN, FbN)                     \
  do {                                                               \
    STAGE(bufP, KPRE(it));                                           \
    asm volatile("s_waitcnt vmcnt(6)\n\ts_barrier" ::: "memory");    \
    READF(FaN, FbN, bufR);                                           \
    MFMAF(FaC, FbC);                                                 \
  } while (0)

  // prologue: tiles 0,1 in flight; read frags(t0) once t0 lands
  STAGE(0, 0);
  STAGE(1, 32);
  asm volatile("s_waitcnt vmcnt(6)\n\ts_barrier" ::: "memory");
  READF(F0a, F0b, 0);

  if (niter >= 4) {  // niter % 4 == 0 for all our shapes >= 4
    for (int itb = 0; itb < niter; itb += 4) {
      ITER(itb + 0, 2, 1, F0a, F0b, F1a, F1b);
      ITER(itb + 1, 3, 2, F1a, F1b, F0a, F0b);
      ITER(itb + 2, 0, 3, F0a, F0b, F1a, F1b);
      ITER(itb + 3, 1, 0, F1a, F1b, F0a, F0b);
    }
  } else {  // niter == 2 (scores, K=64)
    asm volatile("s_waitcnt vmcnt(0)\n\ts_barrier" ::: "memory");
    READF(F1a, F1b, 1);
    MFMAF(F0a, F0b);
    MFMAF(F1a, F1b);
  }
#undef ITER
#undef KPRE
#undef MFMAF
#undef READF
#undef STAGE
  // drain leftover DMAs before LDS is reused by the next block
  asm volatile("s_waitcnt vmcnt(0)" ::: "memory");

  // epilogue; C/D layout: col = lane&15, row = (lane>>4)*4 + reg
  int mbase = m0 + mw + (lane >> 4) * 4;
  int nbase = n0 + nw + (lane & 15);
#pragma unroll
  for (int mt = 0; mt < 4; ++mt) {
#pragma unroll
    for (int nt = 0; nt < 8; ++nt) {
      int n = nbase + nt * 16;
      float bv = bias ? bias[n] : 0.f;
#pragma unroll
      for (int reg = 0; reg < 4; ++reg) {
        int m = mbase + mt * 16 + reg;
        float v = acc[mt][nt][reg] * scale + bv;
        if (RELU) v = fmaxf(v, 0.f);
        if (OUTBF16) {
          bf16* C = (bf16*)Cv + (size_t)blockIdx.z * strideC;
          C[(size_t)m * N + n] = (bf16)v;
        } else {
          float* C = (float*)Cv + (size_t)blockIdx.z * strideC;
          C[(size_t)m * N + n] = v;
        }
      }
    }
  }
}

// ---------------------------------------------------------------------------
// Fused softmax (over k) + attn @ V.  4 q-rows per block, 256 threads.
// ---------------------------------------------------------------------------
__global__ __launch_bounds__(256) void softmax_av(const float* __restrict__ adj,
                                                  const float* __restrict__ V,
                                                  float* __restrict__ out,
                                                  long adjStride) {
  int z = blockIdx.y;
  const float* adjb = adj + (size_t)z * adjStride;
  const float* Vb = V + (size_t)z * (S * D);
  float* outb = out + (size_t)z * (S * D);
  int q0 = blockIdx.x * 4;
  __shared__ __align__(16) float attnL[4][S];
  __shared__ float red[4][4][64];
  __shared__ float rsum[4];
  int tid = threadIdx.x;
  int w = tid >> 6, lane = tid & 63;

  const float* rowp = adjb + (size_t)(q0 + w) * S;
  float lm = -1e30f;
  f32x4 rv[8];
#pragma unroll
  for (int k = 0; k < 8; ++k) {
    rv[k] = *(const f32x4*)&rowp[lane * 4 + k * 256];
    lm = fmaxf(fmaxf(fmaxf(rv[k].x, rv[k].y), fmaxf(rv[k].z, rv[k].w)), lm);
  }
#pragma unroll
  for (int off = 32; off > 0; off >>= 1) lm = fmaxf(lm, __shfl_xor(lm, off));
  float s = 0.f;
#pragma unroll
  for (int k = 0; k < 8; ++k) {
    f32x4 e;
    e.x = __expf(rv[k].x - lm);
    e.y = __expf(rv[k].y - lm);
    e.z = __expf(rv[k].z - lm);
    e.w = __expf(rv[k].w - lm);
    *(f32x4*)&attnL[w][lane * 4 + k * 256] = e;
    s += e.x + e.y + e.z + e.w;
  }
#pragma unroll
  for (int off = 32; off > 0; off >>= 1) s += __shfl_xor(s, off);
  if (lane == 0) rsum[w] = s;
  __syncthreads();

  float acc0 = 0.f, acc1 = 0.f, acc2 = 0.f, acc3 = 0.f;
  int kbase = w * 512;
  for (int kk = 0; kk < 512; kk += 4) {
    int k = kbase + kk;
    float v0 = Vb[(size_t)(k + 0) * D + lane];
    float v1 = Vb[(size_t)(k + 1) * D + lane];
    float v2 = Vb[(size_t)(k + 2) * D + lane];
    float v3 = Vb[(size_t)(k + 3) * D + lane];
    f32x4 a0 = *(const f32x4*)&attnL[0][k];
    f32x4 a1 = *(const f32x4*)&attnL[1][k];
    f32x4 a2 = *(const f32x4*)&attnL[2][k];
    f32x4 a3 = *(const f32x4*)&attnL[3][k];
    acc0 += a0.x * v0 + a0.y * v1 + a0.z * v2 + a0.w * v3;
    acc1 += a1.x * v0 + a1.y * v1 + a1.z * v2 + a1.w * v3;
    acc2 += a2.x * v0 + a2.y * v1 + a2.z * v2 + a2.w * v3;
    acc3 += a3.x * v0 + a3.y * v1 + a3.z * v2 + a3.w * v3;
  }
  red[w][0][lane] = acc0;
  red[w][1][lane] = acc1;
  red[w][2][lane] = acc2;
  red[w][3][lane] = acc3;
  __syncthreads();
  int r = tid >> 6, d = tid & 63;
  float v = red[0][r][d] + red[1][r][d] + red[2][r][d] + red[3][r][d];
  outb[(size_t)(q0 + r) * D + d] = v / rsum[r];
}

// ---------------------------------------------------------------------------
extern "C" void kernel_launch(void* const* d_in, const int* in_sizes, int n_in,
                              void* d_out, int out_size, void* d_ws, size_t ws_size,
                              hipStream_t stream) {
  const float* Q  = (const float*)d_in[0];
  const float* Km = (const float*)d_in[1];
  const float* V  = (const float*)d_in[2];
  const float* W1 = (const float*)d_in[3];
  const float* b1 = (const float*)d_in[4];
  const float* W2 = (const float*)d_in[5];
  const float* b2 = (const float*)d_in[6];
  float* out = (float*)d_out;
  char* ws = (char*)d_ws;

  bf16* W1t  = (bf16*)ws;
  bf16* W2t  = (bf16*)(ws + 16777216);
  bf16* Qb16 = (bf16*)(ws + 33554432);
  bf16* Kb16 = (bf16*)(ws + 35651584);

  transpose_cast<<<dim3(H / 64, S / 64), 256, 0, stream>>>(W1, W1t, S, H);
  transpose_cast<<<dim3(S / 64, H / 64), 256, 0, stream>>>(W2, W2t, H, S);
  cast_bf16<<<dim3(NB * S * D / 1024), 256, 0, stream>>>(Q, Qb16);
  cast_bf16<<<dim3(NB * S * D / 1024), 256, 0, stream>>>(Km, Kb16);

  int G = 1;
  if (ws_size >= 306184192ULL) G = 8;
  else if (ws_size >= 171966464ULL) G = 4;
  else if (ws_size >= 104857600ULL) G = 2;

  bf16* Sc   = (bf16*)(ws + 37748736);
  float* adj = (float*)(ws + 37748736);
  bf16* h    = (bf16*)(ws + 37748736 + (size_t)G * 16777216);

  for (int b0 = 0; b0 < NB; b0 += G) {
    gemm_bt<0, 1><<<dim3(S / 256, S / 128, G), 256, 0, stream>>>(
        Qb16 + (size_t)b0 * S * D, Kb16 + (size_t)b0 * S * D, nullptr, Sc,
        0.125f, S, S, D, (long)S * D, (long)S * D, (long)S * S);
    gemm_bt<1, 1><<<dim3(H / 256, S / 128, G), 256, 0, stream>>>(
        Sc, W1t, b1, h, 1.0f, S, H, S, (long)S * S, 0L, (long)S * H);
    gemm_bt<0, 0><<<dim3(S / 256, S / 128, G), 256, 0, stream>>>(
        h, W2t, b2, adj, 1.0f, S, S, H, (long)S * H, 0L, (long)S * S);
    softmax_av<<<dim3(S / 4, G), 256, 0, stream>>>(
        adj, V + (size_t)b0 * S * D, out + (size_t)b0 * S * D, (long)S * S);
  }
}